// Round 1
// baseline (767.400 us; speedup 1.0000x reference)
//
#include <hip/hip_runtime.h>
#include <cstddef>

// ---------------------------------------------------------------------------
// TorchFovea: foveated Laplacian pyramid blend.
// B=32, C=3, H=360, W=640, LEVEL=5, SIGMA=71, FACTOR=2.
// ---------------------------------------------------------------------------

static __device__ __forceinline__ int refl(int e, int n) {
  // reflect-pad index (no edge duplication), pad <= 2, n >= 4
  if (e < 0) e = -e;
  if (e >= n) e = 2 * n - 2 - e;
  return e;
}

// f0[y][x] = exp(-((x-640)^2 + (y-360)^2) / (2*71*71)), shape 719 x 1279
__global__ void gen_f0_k(float* __restrict__ f0) {
  const int FH = 719, FW = 1279;
  int i = blockIdx.x * blockDim.x + threadIdx.x;
  if (i >= FH * FW) return;
  int y = i / FW;
  int x = i - y * FW;
  float dx = (float)(x - 640);
  float dy = (float)(y - 360);
  float d = dx * dx + dy * dy;
  f0[i] = expf(-d / 10082.0f);
}

// OpenCV-style pyrDown: 5x5 binomial blur w/ reflect pad, keep even coords.
// Batched over blockIdx.z planes. oH=ceil(H/2), oW=ceil(W/2).
__global__ void pyrdown_k(const float* __restrict__ src, float* __restrict__ dst,
                          int H, int W, int oH, int oW) {
  int x = blockIdx.x * blockDim.x + threadIdx.x;
  int y = blockIdx.y * blockDim.y + threadIdx.y;
  int p = blockIdx.z;
  if (x >= oW || y >= oH) return;
  const float k1[5] = {0.0625f, 0.25f, 0.375f, 0.25f, 0.0625f};
  const float* s = src + (size_t)p * H * W;
  float acc = 0.f;
#pragma unroll
  for (int a = 0; a < 5; ++a) {
    int ey = refl(2 * y + a - 2, H);
    float r = 0.f;
#pragma unroll
    for (int b = 0; b < 5; ++b) {
      int ex = refl(2 * x + b - 2, W);
      r += k1[b] * s[ey * W + ex];
    }
    acc += k1[a] * r;
  }
  dst[(size_t)p * oH * oW + y * oW + x] = acc;
}

// Evaluate OpenCV-style pyrUp of src (H x W) at output coord (y, x),
// y in [0, 2H), x in [0, 2W). Zero-insertion upsample + 5x5 blur * 4,
// reflect pad on the upsampled grid. Reflection preserves parity, so
// zero-taps are exactly the odd reflected indices.
static __device__ __forceinline__ float pyrup_eval(const float* __restrict__ s,
                                                   int H, int W, int y, int x) {
  const float k1[5] = {0.0625f, 0.25f, 0.375f, 0.25f, 0.0625f};
  int H2 = 2 * H, W2 = 2 * W;
  float acc = 0.f;
#pragma unroll
  for (int a = 0; a < 5; ++a) {
    int ey = refl(y + a - 2, H2);
    if (ey & 1) continue;
    float r = 0.f;
#pragma unroll
    for (int b = 0; b < 5; ++b) {
      int ex = refl(x + b - 2, W2);
      if (ex & 1) continue;
      r += k1[b] * s[(ey >> 1) * W + (ex >> 1)];
    }
    acc += k1[a] * r;
  }
  return 4.f * acc;
}

// Fused reconstruction step for level i:
//   out(y,x) = pyrup(fprev)(y,x) + (cur(y,x) - pyrup(dnext)(y,x)) * crop(y,x)
// where crop(y,x) = filt[y1+y][x1+x], y1/x1 from per-batch fixation.
// For i = LEVEL-1 pass fprev == dnext (then fv == up, matching the reference's
// fovea initialization fovea = up; fovea += pyr*crop).
__global__ void recon_k(const float* __restrict__ fprev, int Hp, int Wp,
                        const float* __restrict__ dnext, int Hn, int Wn,
                        const float* __restrict__ cur,
                        const float* __restrict__ filt, int fh, int fw,
                        const float* __restrict__ fix, float inv_scale,
                        float* __restrict__ out, int ih, int iw) {
  int x = blockIdx.x * blockDim.x + threadIdx.x;
  int y = blockIdx.y * blockDim.y + threadIdx.y;
  int p = blockIdx.z;
  if (x >= iw || y >= ih) return;
  int b = p / 3;  // C = 3
  // fixations / 2^i  (exact: power-of-two scaling)
  float fx = fix[2 * b + 0] * inv_scale;
  float fy = fix[2 * b + 1] * inv_scale;
  int x1 = (int)(0.5f * (float)fw - fx);  // trunc toward zero; always >= 0
  int y1 = (int)(0.5f * (float)fh - fy);
  float up = pyrup_eval(dnext + (size_t)p * Hn * Wn, Hn, Wn, y, x);
  float fv = (fprev == dnext) ? up
                              : pyrup_eval(fprev + (size_t)p * Hp * Wp, Hp, Wp, y, x);
  float w = filt[(y1 + y) * fw + (x1 + x)];
  float c = cur[(size_t)p * ih * iw + y * iw + x];
  out[(size_t)p * ih * iw + y * iw + x] = fv + (c - up) * w;
}

extern "C" void kernel_launch(void* const* d_in, const int* in_sizes, int n_in,
                              void* d_out, int out_size, void* d_ws, size_t ws_size,
                              hipStream_t stream) {
  const float* images = (const float*)d_in[0];   // (32,3,360,640)
  const float* fix    = (const float*)d_in[1];   // (32,2) = (x,y)
  float* out = (float*)d_out;                    // (32,3,360,640)
  float* ws  = (float*)d_ws;

  const int P = 96;  // 32 * 3 planes

  // ---- workspace layout (floats) ----
  size_t off = 0;
  float* f0 = ws + off; off += (size_t)719 * 1279;   // 919601
  float* f1 = ws + off; off += (size_t)360 * 640;    // 230400
  float* f2 = ws + off; off += (size_t)180 * 320;
  float* f3 = ws + off; off += (size_t)90 * 160;
  float* f4 = ws + off; off += (size_t)45 * 80;
  float* dn1 = ws + off; off += (size_t)P * 180 * 320;
  float* dn2 = ws + off; off += (size_t)P * 90 * 160;
  float* dn3 = ws + off; off += (size_t)P * 45 * 80;
  float* dn4 = ws + off; off += (size_t)P * 23 * 40;
  float* dn5 = ws + off; off += (size_t)P * 12 * 20;
  float* fv4 = ws + off; off += (size_t)P * 23 * 40;
  float* fv3 = ws + off; off += (size_t)P * 45 * 80;
  float* fv2 = ws + off; off += (size_t)P * 90 * 160;
  float* fv1 = ws + off; off += (size_t)P * 180 * 320;
  if (ws_size < off * sizeof(float)) return;  // workspace too small -> loud failure

  dim3 blk(64, 4, 1);
  auto grd = [](int w, int h, int p) {
    return dim3((unsigned)((w + 63) / 64), (unsigned)((h + 3) / 4), (unsigned)p);
  };

  // ---- filters (input-independent but recomputed every call) ----
  gen_f0_k<<<dim3((719 * 1279 + 255) / 256), dim3(256), 0, stream>>>(f0);
  pyrdown_k<<<grd(640, 360, 1), blk, 0, stream>>>(f0, f1, 719, 1279, 360, 640);
  pyrdown_k<<<grd(320, 180, 1), blk, 0, stream>>>(f1, f2, 360, 640, 180, 320);
  pyrdown_k<<<grd(160, 90, 1), blk, 0, stream>>>(f2, f3, 180, 320, 90, 160);
  pyrdown_k<<<grd(80, 45, 1), blk, 0, stream>>>(f3, f4, 90, 160, 45, 80);

  // ---- Gaussian pyramid of the images ----
  pyrdown_k<<<grd(320, 180, P), blk, 0, stream>>>(images, dn1, 360, 640, 180, 320);
  pyrdown_k<<<grd(160, 90, P), blk, 0, stream>>>(dn1, dn2, 180, 320, 90, 160);
  pyrdown_k<<<grd(80, 45, P), blk, 0, stream>>>(dn2, dn3, 90, 160, 45, 80);
  pyrdown_k<<<grd(40, 23, P), blk, 0, stream>>>(dn3, dn4, 45, 80, 23, 40);
  pyrdown_k<<<grd(20, 12, P), blk, 0, stream>>>(dn4, dn5, 23, 40, 12, 20);

  // ---- fused reconstruction (coarse -> fine) ----
  // i=4: fovea = up + (dn4 - up)*crop4, up = pyrup(dn5) cropped to 23x40
  recon_k<<<grd(40, 23, P), blk, 0, stream>>>(dn5, 12, 20, dn5, 12, 20, dn4,
                                              f4, 45, 80, fix, 1.0f / 16.0f,
                                              fv4, 23, 40);
  // i=3
  recon_k<<<grd(80, 45, P), blk, 0, stream>>>(fv4, 23, 40, dn4, 23, 40, dn3,
                                              f3, 90, 160, fix, 1.0f / 8.0f,
                                              fv3, 45, 80);
  // i=2
  recon_k<<<grd(160, 90, P), blk, 0, stream>>>(fv3, 45, 80, dn3, 45, 80, dn2,
                                               f2, 180, 320, fix, 0.25f,
                                               fv2, 90, 160);
  // i=1
  recon_k<<<grd(320, 180, P), blk, 0, stream>>>(fv2, 90, 160, dn2, 90, 160, dn1,
                                                f1, 360, 640, fix, 0.5f,
                                                fv1, 180, 320);
  // i=0 -> final output
  recon_k<<<grd(640, 360, P), blk, 0, stream>>>(fv1, 180, 320, dn1, 180, 320, images,
                                                f0, 719, 1279, fix, 1.0f,
                                                out, 360, 640);
}

// Round 3
// 324.274 us; speedup vs baseline: 2.3665x; 2.3665x over previous
//
#include <hip/hip_runtime.h>
#include <cstddef>

// ---------------------------------------------------------------------------
// TorchFovea: foveated Laplacian pyramid blend.
// B=32, C=3, H=360, W=640, LEVEL=5, SIGMA=71, FACTOR=2.
//
// Round-3: round-2 polyphase kernels with two launch-side fixes:
//  (1) recon2_k grids now use the COARSE dims of the level being upsampled
//      (they were shifted one level too coarse -> 3/4 of each fovea level
//      never written).
//  (2) workspace sub-arrays padded to 16B boundaries (f0 has an odd float
//      count; float2 ops need 8B alignment).
// ---------------------------------------------------------------------------

static __device__ __forceinline__ int refl(int e, int n) {
  // reflect-pad index (no edge duplication), pad <= 2
  if (e < 0) e = -e;
  if (e >= n) e = 2 * n - 2 - e;
  return e;
}

// f0[y][x] = exp(-((x-640)^2 + (y-360)^2) / (2*71*71)), shape 719 x 1279
__global__ void gen_f0_k(float* __restrict__ f0) {
  const int FH = 719, FW = 1279;
  int i = blockIdx.x * blockDim.x + threadIdx.x;
  if (i >= FH * FW) return;
  int y = i / FW;
  int x = i - y * FW;
  float dx = (float)(x - 640);
  float dy = (float)(y - 360);
  f0[i] = expf(-(dx * dx + dy * dy) / 10082.0f);
}

// OpenCV-style pyrDown, 2x2 outputs per thread.
// Thread (X,Y) -> outputs (2Y..2Y+1, 2X..2X+1); needs input rows 4Y-2..4Y+4,
// cols 4X-2..4X+4 (7x7 patch).
__global__ void pyrdown2_k(const float* __restrict__ src, float* __restrict__ dst,
                           int H, int W, int oH, int oW) {
  int X = blockIdx.x * blockDim.x + threadIdx.x;
  int Y = blockIdx.y * blockDim.y + threadIdx.y;
  int p = blockIdx.z;
  int cW = (oW + 1) >> 1, cH = (oH + 1) >> 1;
  if (X >= cW || Y >= cH) return;
  const float* s = src + (size_t)p * H * W;
  int by = 4 * Y - 2, bx = 4 * X - 2;

  float r[7][7];
  if (by >= 0 && by + 6 < H && bx >= 0 && bx + 6 < W && !(W & 1)) {
    const float* q = s + (size_t)by * W + bx;
#pragma unroll
    for (int i = 0; i < 7; ++i) {
      const float* row = q + (size_t)i * W;
      float2 a = *(const float2*)(row);
      float2 b = *(const float2*)(row + 2);
      float2 c = *(const float2*)(row + 4);
      r[i][0] = a.x; r[i][1] = a.y; r[i][2] = b.x; r[i][3] = b.y;
      r[i][4] = c.x; r[i][5] = c.y; r[i][6] = row[6];
    }
  } else {
    int ri[7], ci[7];
#pragma unroll
    for (int i = 0; i < 7; ++i) { ri[i] = refl(by + i, H); ci[i] = refl(bx + i, W); }
#pragma unroll
    for (int i = 0; i < 7; ++i) {
      const float* row = s + (size_t)ri[i] * W;
#pragma unroll
      for (int j = 0; j < 7; ++j) r[i][j] = row[ci[j]];
    }
  }

  const float k0 = 0.0625f, k1 = 0.25f, k2 = 0.375f;
  float v0[7], v1[7];
#pragma unroll
  for (int c = 0; c < 7; ++c) {
    v0[c] = k0 * (r[0][c] + r[4][c]) + k1 * (r[1][c] + r[3][c]) + k2 * r[2][c];
    v1[c] = k0 * (r[2][c] + r[6][c]) + k1 * (r[3][c] + r[5][c]) + k2 * r[4][c];
  }
  float o00 = k0 * (v0[0] + v0[4]) + k1 * (v0[1] + v0[3]) + k2 * v0[2];
  float o01 = k0 * (v0[2] + v0[6]) + k1 * (v0[3] + v0[5]) + k2 * v0[4];
  float o10 = k0 * (v1[0] + v1[4]) + k1 * (v1[1] + v1[3]) + k2 * v1[2];
  float o11 = k0 * (v1[2] + v1[6]) + k1 * (v1[3] + v1[5]) + k2 * v1[4];

  int oy = 2 * Y, ox = 2 * X;  // ox+1 < oW always (oW even)
  float* d = dst + (size_t)p * oH * oW + (size_t)oy * oW + ox;
  *(float2*)d = make_float2(o00, o01);
  if (oy + 1 < oH) *(float2*)(d + oW) = make_float2(o10, o11);
}

// Fused reconstruction, 2x2 outputs per thread at coarse texel (Y,X):
//   out = pyrup(fprev) + (cur - pyrup(dnext)) * crop
// Coarse sources are Hc x Wc (= ceil(ih/2) x ceil(iw/2)); pyrup evaluated via
// polyphase separable weights: even phase [1/8, 3/4, 1/8], odd [1/2, 1/2].
// For i = LEVEL-1 pass fprev == dnext (then fv == up).
__global__ void recon2_k(const float* __restrict__ fprev,
                         const float* __restrict__ dnext, int Hc, int Wc,
                         const float* __restrict__ cur,
                         const float* __restrict__ filt, int fh, int fw,
                         const float* __restrict__ fix, float inv_scale,
                         float* __restrict__ out, int ih, int iw) {
  int X = blockIdx.x * blockDim.x + threadIdx.x;
  int Y = blockIdx.y * blockDim.y + threadIdx.y;
  int p = blockIdx.z;
  if (X >= Wc || Y >= Hc) return;

  // coarse reflection of Y-1, Y+1 (reflection on the 2H grid, even parity):
  int ym = (Y == 0) ? 1 : Y - 1;
  int yp = (Y == Hc - 1) ? Hc - 1 : Y + 1;
  int xm = (X == 0) ? 1 : X - 1;
  int xp = (X == Wc - 1) ? Wc - 1 : X + 1;

  const float we0 = 0.125f, we1 = 0.75f;  // even-phase 3-tap

  const float* dn = dnext + (size_t)p * Hc * Wc;
  const float* r0 = dn + (size_t)ym * Wc;
  const float* r1 = dn + (size_t)Y * Wc;
  const float* r2 = dn + (size_t)yp * Wc;
  float d00 = r0[xm], d01 = r0[X], d02 = r0[xp];
  float d10 = r1[xm], d11 = r1[X], d12 = r1[xp];
  float d20 = r2[xm], d21 = r2[X], d22 = r2[xp];

  float heA = we1 * d01 + we0 * (d00 + d02);
  float heB = we1 * d11 + we0 * (d10 + d12);
  float heC = we1 * d21 + we0 * (d20 + d22);
  float hoA = 0.5f * (d01 + d02);
  float hoB = 0.5f * (d11 + d12);
  float hoC = 0.5f * (d21 + d22);
  float up00 = we1 * heB + we0 * (heA + heC);
  float up01 = we1 * hoB + we0 * (hoA + hoC);
  float up10 = 0.5f * (heB + heC);
  float up11 = 0.5f * (hoB + hoC);

  float fv00, fv01, fv10, fv11;
  if (fprev != dnext) {
    const float* fp = fprev + (size_t)p * Hc * Wc;
    const float* q0 = fp + (size_t)ym * Wc;
    const float* q1 = fp + (size_t)Y * Wc;
    const float* q2 = fp + (size_t)yp * Wc;
    float f00 = q0[xm], f01 = q0[X], f02 = q0[xp];
    float f10 = q1[xm], f11 = q1[X], f12 = q1[xp];
    float f20 = q2[xm], f21 = q2[X], f22 = q2[xp];
    float geA = we1 * f01 + we0 * (f00 + f02);
    float geB = we1 * f11 + we0 * (f10 + f12);
    float geC = we1 * f21 + we0 * (f20 + f22);
    float goA = 0.5f * (f01 + f02);
    float goB = 0.5f * (f11 + f12);
    float goC = 0.5f * (f21 + f22);
    fv00 = we1 * geB + we0 * (geA + geC);
    fv01 = we1 * goB + we0 * (goA + goC);
    fv10 = 0.5f * (geB + geC);
    fv11 = 0.5f * (goB + goC);
  } else {
    fv00 = up00; fv01 = up01; fv10 = up10; fv11 = up11;
  }

  // per-batch crop offset (uniform within block: p is blockIdx.z)
  int b = p / 3;
  float fx = fix[2 * b + 0] * inv_scale;
  float fy = fix[2 * b + 1] * inv_scale;
  int x1 = (int)(0.5f * (float)fw - fx);
  int y1 = (int)(0.5f * (float)fh - fy);

  int oy = 2 * Y, ox = 2 * X;  // ox+1 < iw always (iw even)
  const float* cr = cur + (size_t)p * ih * iw + (size_t)oy * iw + ox;
  const float* fr = filt + (size_t)(y1 + oy) * fw + (x1 + ox);
  float* d = out + (size_t)p * ih * iw + (size_t)oy * iw + ox;

  float2 c0 = *(const float2*)cr;
  float w00 = fr[0], w01 = fr[1];
  *(float2*)d = make_float2(fv00 + (c0.x - up00) * w00,
                            fv01 + (c0.y - up01) * w01);
  if (oy + 1 < ih) {
    float2 c1 = *(const float2*)(cr + iw);
    float w10 = fr[fw], w11 = fr[fw + 1];
    *(float2*)(d + iw) = make_float2(fv10 + (c1.x - up10) * w10,
                                     fv11 + (c1.y - up11) * w11);
  }
}

extern "C" void kernel_launch(void* const* d_in, const int* in_sizes, int n_in,
                              void* d_out, int out_size, void* d_ws, size_t ws_size,
                              hipStream_t stream) {
  const float* images = (const float*)d_in[0];   // (32,3,360,640)
  const float* fix    = (const float*)d_in[1];   // (32,2) = (x,y)
  float* out = (float*)d_out;                    // (32,3,360,640)
  float* ws  = (float*)d_ws;

  const int P = 96;  // 32 * 3 planes

  // ---- workspace layout (floats), each array padded to 16B boundary ----
  size_t off = 0;
  auto alloc = [&](size_t n) { float* p = ws + off; off += (n + 3) & ~(size_t)3; return p; };
  float* f0  = alloc((size_t)719 * 1279);
  float* f1  = alloc((size_t)360 * 640);
  float* f2  = alloc((size_t)180 * 320);
  float* f3  = alloc((size_t)90 * 160);
  float* f4  = alloc((size_t)45 * 80);
  float* dn1 = alloc((size_t)P * 180 * 320);
  float* dn2 = alloc((size_t)P * 90 * 160);
  float* dn3 = alloc((size_t)P * 45 * 80);
  float* dn4 = alloc((size_t)P * 23 * 40);
  float* dn5 = alloc((size_t)P * 12 * 20);
  float* fv4 = alloc((size_t)P * 23 * 40);
  float* fv3 = alloc((size_t)P * 45 * 80);
  float* fv2 = alloc((size_t)P * 90 * 160);
  float* fv1 = alloc((size_t)P * 180 * 320);
  if (ws_size < off * sizeof(float)) return;

  dim3 blk(32, 8, 1);
  auto grd = [](int tx, int ty, int p) {
    return dim3((unsigned)((tx + 31) / 32), (unsigned)((ty + 7) / 8), (unsigned)p);
  };

  // ---- filters (input-independent but recomputed every call) ----
  gen_f0_k<<<dim3((719 * 1279 + 255) / 256), dim3(256), 0, stream>>>(f0);
  // pyrdown thread extents are halves (ceil) of the OUTPUT dims
  pyrdown2_k<<<grd(320, 180, 1), blk, 0, stream>>>(f0, f1, 719, 1279, 360, 640);
  pyrdown2_k<<<grd(160, 90, 1), blk, 0, stream>>>(f1, f2, 360, 640, 180, 320);
  pyrdown2_k<<<grd(80, 45, 1), blk, 0, stream>>>(f2, f3, 180, 320, 90, 160);
  pyrdown2_k<<<grd(40, 23, 1), blk, 0, stream>>>(f3, f4, 90, 160, 45, 80);

  // ---- Gaussian pyramid of the images ----
  pyrdown2_k<<<grd(160, 90, P), blk, 0, stream>>>(images, dn1, 360, 640, 180, 320);
  pyrdown2_k<<<grd(80, 45, P), blk, 0, stream>>>(dn1, dn2, 180, 320, 90, 160);
  pyrdown2_k<<<grd(40, 23, P), blk, 0, stream>>>(dn2, dn3, 90, 160, 45, 80);
  pyrdown2_k<<<grd(20, 12, P), blk, 0, stream>>>(dn3, dn4, 45, 80, 23, 40);
  pyrdown2_k<<<grd(10, 6, P), blk, 0, stream>>>(dn4, dn5, 23, 40, 12, 20);

  // ---- fused reconstruction (coarse -> fine) ----
  // recon grid extents = coarse dims (Wc, Hc) of the level being upsampled.
  // i=4: fv4 = up + (dn4 - up)*crop4, up = pyrup(dn5) cropped to 23x40
  recon2_k<<<grd(20, 12, P), blk, 0, stream>>>(dn5, dn5, 12, 20, dn4,
                                               f4, 45, 80, fix, 1.0f / 16.0f,
                                               fv4, 23, 40);
  // i=3: coarse = 23x40
  recon2_k<<<grd(40, 23, P), blk, 0, stream>>>(fv4, dn4, 23, 40, dn3,
                                               f3, 90, 160, fix, 1.0f / 8.0f,
                                               fv3, 45, 80);
  // i=2: coarse = 45x80
  recon2_k<<<grd(80, 45, P), blk, 0, stream>>>(fv3, dn3, 45, 80, dn2,
                                               f2, 180, 320, fix, 0.25f,
                                               fv2, 90, 160);
  // i=1: coarse = 90x160
  recon2_k<<<grd(160, 90, P), blk, 0, stream>>>(fv2, dn2, 90, 160, dn1,
                                                f1, 360, 640, fix, 0.5f,
                                                fv1, 180, 320);
  // i=0: coarse = 180x320 -> final output
  recon2_k<<<grd(320, 180, P), blk, 0, stream>>>(fv1, dn1, 180, 320, images,
                                                 f0, 719, 1279, fix, 1.0f,
                                                 out, 360, 640);
}

// Round 4
// 297.403 us; speedup vs baseline: 2.5803x; 1.0904x over previous
//
#include <hip/hip_runtime.h>
#include <cstddef>

// ---------------------------------------------------------------------------
// TorchFovea: foveated Laplacian pyramid blend.
// B=32, C=3, H=360, W=640, LEVEL=5, SIGMA=71, FACTOR=2.
//
// Round-4:
//  - pyrdown_y2_k: 2 outputs in y, 1 in x -> all global loads fully coalesced
//    (8B lane stride float2). f0 stored with padded pitch 1280 so the filter
//    pyrdown also takes the vector fast path.
//  - recon4_k: 2 coarse texels -> 2x4 outputs per thread, float4 cur/out.
//  - filter pyrdowns ride as plane z==P of the image pyrdown launches.
// ---------------------------------------------------------------------------

static __device__ __forceinline__ int refl(int e, int n) {
  if (e < 0) e = -e;
  if (e >= n) e = 2 * n - 2 - e;
  return e;
}

static __device__ __forceinline__ float4 loadu4(const float* p) {
  float4 v; __builtin_memcpy(&v, p, sizeof(float4)); return v;
}

// f0[y][x] = exp(-((x-640)^2 + (y-360)^2) / (2*71*71)); logical 719x1279,
// stored with pitch 1280 (col 1279 is pad, written but never read).
__global__ void gen_f0_k(float* __restrict__ f0) {
  const int FH = 719, FWS = 1280;
  int i = blockIdx.x * blockDim.x + threadIdx.x;
  if (i >= FH * FWS) return;
  int y = i / FWS;
  int x = i - y * FWS;
  float dx = (float)(x - 640), dy = (float)(y - 360);
  f0[i] = expf(-(dx * dx + dy * dy) / 10082.0f);
}

// OpenCV-style pyrDown: 2 outputs in y per thread, 1 in x (coalesced loads).
// Output rows 2Y, 2Y+1 need input rows 4Y-2..4Y+4 (7) and cols 2x-2..2x+2 (5).
// Plane z==P (if fsrc) processes the filter plane fsrc->fdst (same dims).
// sstride = row pitch (== W except f0: W=1279, pitch=1280).
__global__ __launch_bounds__(256) void pyrdown_y2_k(
    const float* __restrict__ src, float* __restrict__ dst,
    const float* __restrict__ fsrc, float* __restrict__ fdst,
    int H, int W, int sstride, int oH, int oW, int P) {
  int x = blockIdx.x * blockDim.x + threadIdx.x;
  int Y = blockIdx.y * blockDim.y + threadIdx.y;
  int nYP = (oH + 1) >> 1;
  if (x >= oW || Y >= nYP) return;
  int p = blockIdx.z;
  const float* s; float* d;
  if (p < P) { s = src + (size_t)p * H * sstride; d = dst + (size_t)p * oH * oW; }
  else       { s = fsrc; d = fdst; }

  const float k0 = 0.0625f, k1 = 0.25f, k2 = 0.375f;
  const float kv[5] = {k0, k1, k2, k1, k0};
  bool fastx = (x >= 1) && (2 * x + 2 < W);
  int c0i = 0, c1i = 0, c2i = 0, c3i = 0, c4i = 0;
  if (!fastx) {
    c0i = refl(2 * x - 2, W); c1i = refl(2 * x - 1, W); c2i = 2 * x;
    c3i = refl(2 * x + 1, W); c4i = refl(2 * x + 2, W);
  }
  float v0a = 0, v0b = 0, v0c = 0, v0d = 0, v0e = 0;
  float v1a = 0, v1b = 0, v1c = 0, v1d = 0, v1e = 0;
#pragma unroll
  for (int a = 0; a < 7; ++a) {
    int gy = refl(4 * Y - 2 + a, H);
    const float* row = s + (size_t)gy * sstride;
    float e0, e1, e2, e3, e4;
    if (fastx) {
      float2 u = *(const float2*)(row + 2 * x - 2);
      float2 v = *(const float2*)(row + 2 * x);
      e0 = u.x; e1 = u.y; e2 = v.x; e3 = v.y; e4 = row[2 * x + 2];
    } else {
      e0 = row[c0i]; e1 = row[c1i]; e2 = row[c2i]; e3 = row[c3i]; e4 = row[c4i];
    }
    if (a < 5) {
      float w = kv[a];
      v0a += w * e0; v0b += w * e1; v0c += w * e2; v0d += w * e3; v0e += w * e4;
    }
    if (a >= 2) {
      float w = kv[a - 2];
      v1a += w * e0; v1b += w * e1; v1c += w * e2; v1d += w * e3; v1e += w * e4;
    }
  }
  float o0 = k0 * (v0a + v0e) + k1 * (v0b + v0d) + k2 * v0c;
  float o1 = k0 * (v1a + v1e) + k1 * (v1b + v1d) + k2 * v1c;
  int oy = 2 * Y;
  d[(size_t)oy * oW + x] = o0;
  if (oy + 1 < oH) d[(size_t)(oy + 1) * oW + x] = o1;
}

// Fused reconstruction, 2 coarse texels (cols 2*X2, 2*X2+1) x 1 coarse row
// -> 2x4 fine outputs:  out = pyrup(fprev) + (cur - pyrup(dnext)) * crop.
// Polyphase pyrup: even phase [1/8, 3/4, 1/8], odd [1/2, 1/2].
// fprev == dnext  =>  fv == up (level LEVEL-1 initialization).
// fw/fh are LOGICAL filter dims (crop math); fstride is the row pitch.
__global__ __launch_bounds__(256) void recon4_k(
    const float* __restrict__ fprev, const float* __restrict__ dnext,
    int Hc, int Wc, const float* __restrict__ cur,
    const float* __restrict__ filt, int fh, int fw, int fstride,
    const float* __restrict__ fix, float inv_scale,
    float* __restrict__ out, int ih, int iw) {
  int X2 = blockIdx.x * blockDim.x + threadIdx.x;
  int Y  = blockIdx.y * blockDim.y + threadIdx.y;
  int Wp = Wc >> 1;
  if (X2 >= Wp || Y >= Hc) return;
  int p = blockIdx.z;

  int ry[3];
  ry[0] = (Y == 0) ? 1 : Y - 1;
  ry[1] = Y;
  ry[2] = (Y == Hc - 1) ? Hc - 1 : Y + 1;
  int c0 = 2 * X2;
  const float* dn  = dnext + (size_t)p * Hc * Wc;
  const float* fpv = fprev + (size_t)p * Hc * Wc;
  bool two = (fprev != dnext);
  bool interior = (X2 >= 1) && (X2 <= Wp - 2);

  float dm[3], da[3], db[3], dq[3];
  float em[3], ea[3], eb[3], eq[3];
  if (interior) {
#pragma unroll
    for (int r = 0; r < 3; ++r) {
      const float* q = dn + (size_t)ry[r] * Wc + c0;
      float2 A = *(const float2*)(q - 2);
      float2 B = *(const float2*)(q);
      float2 C = *(const float2*)(q + 2);
      dm[r] = A.y; da[r] = B.x; db[r] = B.y; dq[r] = C.x;
    }
    if (two) {
#pragma unroll
      for (int r = 0; r < 3; ++r) {
        const float* q = fpv + (size_t)ry[r] * Wc + c0;
        float2 A = *(const float2*)(q - 2);
        float2 B = *(const float2*)(q);
        float2 C = *(const float2*)(q + 2);
        em[r] = A.y; ea[r] = B.x; eb[r] = B.y; eq[r] = C.x;
      }
    }
  } else {
    int cm = (c0 == 0) ? 1 : c0 - 1;
    int cp = (c0 + 2 >= Wc) ? (Wc - 1) : c0 + 2;
#pragma unroll
    for (int r = 0; r < 3; ++r) {
      const float* row = dn + (size_t)ry[r] * Wc;
      dm[r] = row[cm]; da[r] = row[c0]; db[r] = row[c0 + 1]; dq[r] = row[cp];
    }
    if (two) {
#pragma unroll
      for (int r = 0; r < 3; ++r) {
        const float* row = fpv + (size_t)ry[r] * Wc;
        em[r] = row[cm]; ea[r] = row[c0]; eb[r] = row[c0 + 1]; eq[r] = row[cp];
      }
    }
  }

  const float w0 = 0.125f, w1 = 0.75f;
  float heA[3], hoA[3], heB[3], hoB[3];
#pragma unroll
  for (int r = 0; r < 3; ++r) {
    heA[r] = w1 * da[r] + w0 * (dm[r] + db[r]);
    hoA[r] = 0.5f * (da[r] + db[r]);
    heB[r] = w1 * db[r] + w0 * (da[r] + dq[r]);
    hoB[r] = 0.5f * (db[r] + dq[r]);
  }
  float u00 = w1 * heA[1] + w0 * (heA[0] + heA[2]);
  float u01 = w1 * hoA[1] + w0 * (hoA[0] + hoA[2]);
  float u02 = w1 * heB[1] + w0 * (heB[0] + heB[2]);
  float u03 = w1 * hoB[1] + w0 * (hoB[0] + hoB[2]);
  float u10 = 0.5f * (heA[1] + heA[2]);
  float u11 = 0.5f * (hoA[1] + hoA[2]);
  float u12 = 0.5f * (heB[1] + heB[2]);
  float u13 = 0.5f * (hoB[1] + hoB[2]);

  float f00, f01, f02, f03, f10, f11, f12, f13;
  if (two) {
    float geA[3], goA[3], geB[3], goB[3];
#pragma unroll
    for (int r = 0; r < 3; ++r) {
      geA[r] = w1 * ea[r] + w0 * (em[r] + eb[r]);
      goA[r] = 0.5f * (ea[r] + eb[r]);
      geB[r] = w1 * eb[r] + w0 * (ea[r] + eq[r]);
      goB[r] = 0.5f * (eb[r] + eq[r]);
    }
    f00 = w1 * geA[1] + w0 * (geA[0] + geA[2]);
    f01 = w1 * goA[1] + w0 * (goA[0] + goA[2]);
    f02 = w1 * geB[1] + w0 * (geB[0] + geB[2]);
    f03 = w1 * goB[1] + w0 * (goB[0] + goB[2]);
    f10 = 0.5f * (geA[1] + geA[2]);
    f11 = 0.5f * (goA[1] + goA[2]);
    f12 = 0.5f * (geB[1] + geB[2]);
    f13 = 0.5f * (goB[1] + goB[2]);
  } else {
    f00 = u00; f01 = u01; f02 = u02; f03 = u03;
    f10 = u10; f11 = u11; f12 = u12; f13 = u13;
  }

  int b = p / 3;
  float fxv = fix[2 * b + 0] * inv_scale;
  float fyv = fix[2 * b + 1] * inv_scale;
  int x1 = (int)(0.5f * (float)fw - fxv);
  int y1 = (int)(0.5f * (float)fh - fyv);

  int oy = 2 * Y, ox = 4 * X2;
  const float* crow = cur + (size_t)p * ih * iw + (size_t)oy * iw + ox;
  const float* frow = filt + (size_t)(y1 + oy) * fstride + (x1 + ox);
  float* orow = out + (size_t)p * ih * iw + (size_t)oy * iw + ox;

  float4 cv = *(const float4*)crow;
  float4 wv = loadu4(frow);
  float4 r0v;
  r0v.x = f00 + (cv.x - u00) * wv.x;
  r0v.y = f01 + (cv.y - u01) * wv.y;
  r0v.z = f02 + (cv.z - u02) * wv.z;
  r0v.w = f03 + (cv.w - u03) * wv.w;
  *(float4*)orow = r0v;
  if (oy + 1 < ih) {
    float4 cv1 = *(const float4*)(crow + iw);
    float4 wv1 = loadu4(frow + fstride);
    float4 r1v;
    r1v.x = f10 + (cv1.x - u10) * wv1.x;
    r1v.y = f11 + (cv1.y - u11) * wv1.y;
    r1v.z = f12 + (cv1.z - u12) * wv1.z;
    r1v.w = f13 + (cv1.w - u13) * wv1.w;
    *(float4*)(orow + iw) = r1v;
  }
}

extern "C" void kernel_launch(void* const* d_in, const int* in_sizes, int n_in,
                              void* d_out, int out_size, void* d_ws, size_t ws_size,
                              hipStream_t stream) {
  const float* images = (const float*)d_in[0];   // (32,3,360,640)
  const float* fix    = (const float*)d_in[1];   // (32,2) = (x,y)
  float* out = (float*)d_out;                    // (32,3,360,640)
  float* ws  = (float*)d_ws;

  const int P = 96;  // 32 * 3 planes

  // ---- workspace layout (floats), 16B-aligned blocks ----
  size_t off = 0;
  auto alloc = [&](size_t n) { float* p = ws + off; off += (n + 3) & ~(size_t)3; return p; };
  float* f0  = alloc((size_t)719 * 1280);  // pitch 1280 (logical 1279)
  float* f1  = alloc((size_t)360 * 640);
  float* f2  = alloc((size_t)180 * 320);
  float* f3  = alloc((size_t)90 * 160);
  float* f4  = alloc((size_t)45 * 80);
  float* dn1 = alloc((size_t)P * 180 * 320);
  float* dn2 = alloc((size_t)P * 90 * 160);
  float* dn3 = alloc((size_t)P * 45 * 80);
  float* dn4 = alloc((size_t)P * 23 * 40);
  float* dn5 = alloc((size_t)P * 12 * 20);
  float* fv4 = alloc((size_t)P * 23 * 40);
  float* fv3 = alloc((size_t)P * 45 * 80);
  float* fv2 = alloc((size_t)P * 90 * 160);
  float* fv1 = alloc((size_t)P * 180 * 320);
  if (ws_size < off * sizeof(float)) return;

  dim3 blk(64, 4, 1);
  auto grd = [](int tx, int ty, int p) {
    return dim3((unsigned)((tx + 63) / 64), (unsigned)((ty + 3) / 4), (unsigned)p);
  };

  // ---- f0 (padded pitch) ----
  gen_f0_k<<<dim3((719 * 1280 + 255) / 256), dim3(256), 0, stream>>>(f0);

  // ---- f0 -> f1 (filter-only launch: P=0, plane 0 is the filter) ----
  pyrdown_y2_k<<<grd(640, 180, 1), blk, 0, stream>>>(
      nullptr, nullptr, f0, f1, 719, 1279, 1280, 360, 640, 0);

  // ---- image pyramid with filter plane riding as z==P ----
  pyrdown_y2_k<<<grd(320, 90, P + 1), blk, 0, stream>>>(
      images, dn1, f1, f2, 360, 640, 640, 180, 320, P);
  pyrdown_y2_k<<<grd(160, 45, P + 1), blk, 0, stream>>>(
      dn1, dn2, f2, f3, 180, 320, 320, 90, 160, P);
  pyrdown_y2_k<<<grd(80, 23, P + 1), blk, 0, stream>>>(
      dn2, dn3, f3, f4, 90, 160, 160, 45, 80, P);
  pyrdown_y2_k<<<grd(40, 12, P), blk, 0, stream>>>(
      dn3, dn4, nullptr, nullptr, 45, 80, 80, 23, 40, P);
  pyrdown_y2_k<<<grd(20, 6, P), blk, 0, stream>>>(
      dn4, dn5, nullptr, nullptr, 23, 40, 40, 12, 20, P);

  // ---- fused reconstruction (coarse -> fine); grid = (Wc/2, Hc) ----
  recon4_k<<<grd(10, 12, P), blk, 0, stream>>>(
      dn5, dn5, 12, 20, dn4, f4, 45, 80, 80, fix, 1.0f / 16.0f, fv4, 23, 40);
  recon4_k<<<grd(20, 23, P), blk, 0, stream>>>(
      fv4, dn4, 23, 40, dn3, f3, 90, 160, 160, fix, 1.0f / 8.0f, fv3, 45, 80);
  recon4_k<<<grd(40, 45, P), blk, 0, stream>>>(
      fv3, dn3, 45, 80, dn2, f2, 180, 320, 320, fix, 0.25f, fv2, 90, 160);
  recon4_k<<<grd(80, 90, P), blk, 0, stream>>>(
      fv2, dn2, 90, 160, dn1, f1, 360, 640, 640, fix, 0.5f, fv1, 180, 320);
  recon4_k<<<grd(160, 180, P), blk, 0, stream>>>(
      fv1, dn1, 180, 320, images, f0, 719, 1279, 1280, fix, 1.0f, out, 360, 640);
}

// Round 5
// 277.301 us; speedup vs baseline: 2.7674x; 1.0725x over previous
//
#include <hip/hip_runtime.h>
#include <cstddef>

// ---------------------------------------------------------------------------
// TorchFovea: foveated Laplacian pyramid blend.
// B=32, C=3, H=360, W=640, LEVEL=5, SIGMA=71, FACTOR=2.
//
// Round-5: LDS-staged pyrdown (pyrdown_lds_k).
//   Round-4's pyrdown was latency-bound (VALUBusy 18%, HBM 15%, ~26
//   outstanding lines/CU): per-row load->accumulate forced a waitcnt per row
//   at VGPR_Count=28. Now each block stages its 19-row window into LDS with
//   independent coalesced float2 loads (high MLP), then computes from LDS.
//   Even/odd column split keeps LDS lane-stride 1 (conflict-free).
// recon4_k unchanged from round 4.
// ---------------------------------------------------------------------------

static __device__ __forceinline__ int refl(int e, int n) {
  if (e < 0) e = -e;
  if (e >= n) e = 2 * n - 2 - e;
  return e;
}

static __device__ __forceinline__ float4 loadu4(const float* p) {
  float4 v; __builtin_memcpy(&v, p, sizeof(float4)); return v;
}

// f0[y][x] = exp(-((x-640)^2 + (y-360)^2) / (2*71*71)); logical 719x1279,
// stored with pitch 1280 (col 1279 is pad, written but never read).
__global__ void gen_f0_k(float* __restrict__ f0) {
  const int FH = 719, FWS = 1280;
  int i = blockIdx.x * blockDim.x + threadIdx.x;
  if (i >= FH * FWS) return;
  int y = i / FWS;
  int x = i - y * FWS;
  float dx = (float)(x - 640), dy = (float)(y - 360);
  f0[i] = expf(-(dx * dx + dy * dy) / 10082.0f);
}

// OpenCV-style pyrDown, LDS-staged. Block = 64x4 threads -> output tile
// 64 cols x 8 rows (thread (tx,ty): out col x0+tx, out rows 2(4Yb+ty)+{0,1}).
// Input window: rows 16Yb-2 .. 16Yb+16 (19), cols 2x0-2 .. 2x0+2*cols+1,
// staged as (even,odd) column pairs: pair k <-> global cols 2x0-2+2k, +1.
// Plane z==P (if fsrc) processes the filter plane fsrc->fdst (same dims).
// sstride = row pitch (== W except f0: W=1279, pitch=1280).
__global__ __launch_bounds__(256) void pyrdown_lds_k(
    const float* __restrict__ src, float* __restrict__ dst,
    const float* __restrict__ fsrc, float* __restrict__ fdst,
    int H, int W, int sstride, int oH, int oW, int P) {
  __shared__ float te[19][68];   // even cols
  __shared__ float to_[19][68];  // odd cols
  int tx = threadIdx.x;          // 0..63
  int ty = threadIdx.y;          // 0..3
  int x0 = blockIdx.x * 64;
  int Yb = blockIdx.y;
  int p  = blockIdx.z;
  const float* s; float* d;
  if (p < P) { s = src + (size_t)p * H * sstride; d = dst + (size_t)p * oH * oW; }
  else       { s = fsrc; d = fdst; }

  int cols  = min(64, oW - x0);
  int npair = cols + 2;          // <= 66
  int gr0 = 16 * Yb - 2;
  int gc0 = 2 * x0 - 2;

  // ---- stage: rows r = ty + 4i, pairs k = tx + 64j ----
#pragma unroll
  for (int i = 0; i < 5; ++i) {
    int r = ty + 4 * i;
    if (r < 19) {
      int gy = refl(gr0 + r, H);
      const float* row = s + (size_t)gy * sstride;
#pragma unroll
      for (int j = 0; j < 2; ++j) {
        int k = tx + 64 * j;
        if (k < npair) {
          int gc = gc0 + 2 * k;
          float a, b;
          if (gc >= 0 && gc + 1 < W) {
            float2 v = *(const float2*)(row + gc);
            a = v.x; b = v.y;
          } else {
            a = row[refl(gc, W)];
            b = row[refl(gc + 1, W)];
          }
          te[r][k] = a;
          to_[r][k] = b;
        }
      }
    }
  }
  __syncthreads();

  // ---- compute: horizontal 5-tap from LDS, then vertical 5-tap ----
  int x = x0 + tx;
  int Y = 4 * Yb + ty;
  int nYP = (oH + 1) >> 1;
  if (x < oW && Y < nYP) {
    const float k0 = 0.0625f, k1 = 0.25f, k2 = 0.375f;
    float h[7];
#pragma unroll
    for (int a = 0; a < 7; ++a) {
      int r = 4 * ty + a;
      float e0 = te[r][tx], e2 = te[r][tx + 1], e4 = te[r][tx + 2];
      float e1 = to_[r][tx], e3 = to_[r][tx + 1];
      h[a] = k0 * (e0 + e4) + k1 * (e1 + e3) + k2 * e2;
    }
    float o0 = k0 * (h[0] + h[4]) + k1 * (h[1] + h[3]) + k2 * h[2];
    float o1 = k0 * (h[2] + h[6]) + k1 * (h[3] + h[5]) + k2 * h[4];
    int oy = 2 * Y;
    d[(size_t)oy * oW + x] = o0;
    if (oy + 1 < oH) d[(size_t)(oy + 1) * oW + x] = o1;
  }
}

// Fused reconstruction, 2 coarse texels (cols 2*X2, 2*X2+1) x 1 coarse row
// -> 2x4 fine outputs:  out = pyrup(fprev) + (cur - pyrup(dnext)) * crop.
// Polyphase pyrup: even phase [1/8, 3/4, 1/8], odd [1/2, 1/2].
// fprev == dnext  =>  fv == up (level LEVEL-1 initialization).
// fw/fh are LOGICAL filter dims (crop math); fstride is the row pitch.
__global__ __launch_bounds__(256) void recon4_k(
    const float* __restrict__ fprev, const float* __restrict__ dnext,
    int Hc, int Wc, const float* __restrict__ cur,
    const float* __restrict__ filt, int fh, int fw, int fstride,
    const float* __restrict__ fix, float inv_scale,
    float* __restrict__ out, int ih, int iw) {
  int X2 = blockIdx.x * blockDim.x + threadIdx.x;
  int Y  = blockIdx.y * blockDim.y + threadIdx.y;
  int Wp = Wc >> 1;
  if (X2 >= Wp || Y >= Hc) return;
  int p = blockIdx.z;

  int ry[3];
  ry[0] = (Y == 0) ? 1 : Y - 1;
  ry[1] = Y;
  ry[2] = (Y == Hc - 1) ? Hc - 1 : Y + 1;
  int c0 = 2 * X2;
  const float* dn  = dnext + (size_t)p * Hc * Wc;
  const float* fpv = fprev + (size_t)p * Hc * Wc;
  bool two = (fprev != dnext);
  bool interior = (X2 >= 1) && (X2 <= Wp - 2);

  float dm[3], da[3], db[3], dq[3];
  float em[3], ea[3], eb[3], eq[3];
  if (interior) {
#pragma unroll
    for (int r = 0; r < 3; ++r) {
      const float* q = dn + (size_t)ry[r] * Wc + c0;
      float2 A = *(const float2*)(q - 2);
      float2 B = *(const float2*)(q);
      float2 C = *(const float2*)(q + 2);
      dm[r] = A.y; da[r] = B.x; db[r] = B.y; dq[r] = C.x;
    }
    if (two) {
#pragma unroll
      for (int r = 0; r < 3; ++r) {
        const float* q = fpv + (size_t)ry[r] * Wc + c0;
        float2 A = *(const float2*)(q - 2);
        float2 B = *(const float2*)(q);
        float2 C = *(const float2*)(q + 2);
        em[r] = A.y; ea[r] = B.x; eb[r] = B.y; eq[r] = C.x;
      }
    }
  } else {
    int cm = (c0 == 0) ? 1 : c0 - 1;
    int cp = (c0 + 2 >= Wc) ? (Wc - 1) : c0 + 2;
#pragma unroll
    for (int r = 0; r < 3; ++r) {
      const float* row = dn + (size_t)ry[r] * Wc;
      dm[r] = row[cm]; da[r] = row[c0]; db[r] = row[c0 + 1]; dq[r] = row[cp];
    }
    if (two) {
#pragma unroll
      for (int r = 0; r < 3; ++r) {
        const float* row = fpv + (size_t)ry[r] * Wc;
        em[r] = row[cm]; ea[r] = row[c0]; eb[r] = row[c0 + 1]; eq[r] = row[cp];
      }
    }
  }

  const float w0 = 0.125f, w1 = 0.75f;
  float heA[3], hoA[3], heB[3], hoB[3];
#pragma unroll
  for (int r = 0; r < 3; ++r) {
    heA[r] = w1 * da[r] + w0 * (dm[r] + db[r]);
    hoA[r] = 0.5f * (da[r] + db[r]);
    heB[r] = w1 * db[r] + w0 * (da[r] + dq[r]);
    hoB[r] = 0.5f * (db[r] + dq[r]);
  }
  float u00 = w1 * heA[1] + w0 * (heA[0] + heA[2]);
  float u01 = w1 * hoA[1] + w0 * (hoA[0] + hoA[2]);
  float u02 = w1 * heB[1] + w0 * (heB[0] + heB[2]);
  float u03 = w1 * hoB[1] + w0 * (hoB[0] + hoB[2]);
  float u10 = 0.5f * (heA[1] + heA[2]);
  float u11 = 0.5f * (hoA[1] + hoA[2]);
  float u12 = 0.5f * (heB[1] + heB[2]);
  float u13 = 0.5f * (hoB[1] + hoB[2]);

  float f00, f01, f02, f03, f10, f11, f12, f13;
  if (two) {
    float geA[3], goA[3], geB[3], goB[3];
#pragma unroll
    for (int r = 0; r < 3; ++r) {
      geA[r] = w1 * ea[r] + w0 * (em[r] + eb[r]);
      goA[r] = 0.5f * (ea[r] + eb[r]);
      geB[r] = w1 * eb[r] + w0 * (ea[r] + eq[r]);
      goB[r] = 0.5f * (eb[r] + eq[r]);
    }
    f00 = w1 * geA[1] + w0 * (geA[0] + geA[2]);
    f01 = w1 * goA[1] + w0 * (goA[0] + goA[2]);
    f02 = w1 * geB[1] + w0 * (geB[0] + geB[2]);
    f03 = w1 * goB[1] + w0 * (goB[0] + goB[2]);
    f10 = 0.5f * (geA[1] + geA[2]);
    f11 = 0.5f * (goA[1] + goA[2]);
    f12 = 0.5f * (geB[1] + geB[2]);
    f13 = 0.5f * (goB[1] + goB[2]);
  } else {
    f00 = u00; f01 = u01; f02 = u02; f03 = u03;
    f10 = u10; f11 = u11; f12 = u12; f13 = u13;
  }

  int b = p / 3;
  float fxv = fix[2 * b + 0] * inv_scale;
  float fyv = fix[2 * b + 1] * inv_scale;
  int x1 = (int)(0.5f * (float)fw - fxv);
  int y1 = (int)(0.5f * (float)fh - fyv);

  int oy = 2 * Y, ox = 4 * X2;
  const float* crow = cur + (size_t)p * ih * iw + (size_t)oy * iw + ox;
  const float* frow = filt + (size_t)(y1 + oy) * fstride + (x1 + ox);
  float* orow = out + (size_t)p * ih * iw + (size_t)oy * iw + ox;

  float4 cv = *(const float4*)crow;
  float4 wv = loadu4(frow);
  float4 r0v;
  r0v.x = f00 + (cv.x - u00) * wv.x;
  r0v.y = f01 + (cv.y - u01) * wv.y;
  r0v.z = f02 + (cv.z - u02) * wv.z;
  r0v.w = f03 + (cv.w - u03) * wv.w;
  *(float4*)orow = r0v;
  if (oy + 1 < ih) {
    float4 cv1 = *(const float4*)(crow + iw);
    float4 wv1 = loadu4(frow + fstride);
    float4 r1v;
    r1v.x = f10 + (cv1.x - u10) * wv1.x;
    r1v.y = f11 + (cv1.y - u11) * wv1.y;
    r1v.z = f12 + (cv1.z - u12) * wv1.z;
    r1v.w = f13 + (cv1.w - u13) * wv1.w;
    *(float4*)(orow + iw) = r1v;
  }
}

extern "C" void kernel_launch(void* const* d_in, const int* in_sizes, int n_in,
                              void* d_out, int out_size, void* d_ws, size_t ws_size,
                              hipStream_t stream) {
  const float* images = (const float*)d_in[0];   // (32,3,360,640)
  const float* fix    = (const float*)d_in[1];   // (32,2) = (x,y)
  float* out = (float*)d_out;                    // (32,3,360,640)
  float* ws  = (float*)d_ws;

  const int P = 96;  // 32 * 3 planes

  // ---- workspace layout (floats), 16B-aligned blocks ----
  size_t off = 0;
  auto alloc = [&](size_t n) { float* p = ws + off; off += (n + 3) & ~(size_t)3; return p; };
  float* f0  = alloc((size_t)719 * 1280);  // pitch 1280 (logical 1279)
  float* f1  = alloc((size_t)360 * 640);
  float* f2  = alloc((size_t)180 * 320);
  float* f3  = alloc((size_t)90 * 160);
  float* f4  = alloc((size_t)45 * 80);
  float* dn1 = alloc((size_t)P * 180 * 320);
  float* dn2 = alloc((size_t)P * 90 * 160);
  float* dn3 = alloc((size_t)P * 45 * 80);
  float* dn4 = alloc((size_t)P * 23 * 40);
  float* dn5 = alloc((size_t)P * 12 * 20);
  float* fv4 = alloc((size_t)P * 23 * 40);
  float* fv3 = alloc((size_t)P * 45 * 80);
  float* fv2 = alloc((size_t)P * 90 * 160);
  float* fv1 = alloc((size_t)P * 180 * 320);
  if (ws_size < off * sizeof(float)) return;

  dim3 blk(64, 4, 1);
  // pyrdown grid: x covers oW in 64-col tiles; y covers ceil(oH/2) in 4s
  auto pgrd = [](int oW, int oH, int p) {
    int nYP = (oH + 1) / 2;
    return dim3((unsigned)((oW + 63) / 64), (unsigned)((nYP + 3) / 4), (unsigned)p);
  };
  auto grd = [](int tx, int ty, int p) {
    return dim3((unsigned)((tx + 63) / 64), (unsigned)((ty + 3) / 4), (unsigned)p);
  };

  // ---- f0 (padded pitch) ----
  gen_f0_k<<<dim3((719 * 1280 + 255) / 256), dim3(256), 0, stream>>>(f0);

  // ---- f0 -> f1 (filter-only launch: P=0, plane 0 is the filter) ----
  pyrdown_lds_k<<<pgrd(640, 360, 1), blk, 0, stream>>>(
      nullptr, nullptr, f0, f1, 719, 1279, 1280, 360, 640, 0);

  // ---- image pyramid with filter plane riding as z==P ----
  pyrdown_lds_k<<<pgrd(320, 180, P + 1), blk, 0, stream>>>(
      images, dn1, f1, f2, 360, 640, 640, 180, 320, P);
  pyrdown_lds_k<<<pgrd(160, 90, P + 1), blk, 0, stream>>>(
      dn1, dn2, f2, f3, 180, 320, 320, 90, 160, P);
  pyrdown_lds_k<<<pgrd(80, 45, P + 1), blk, 0, stream>>>(
      dn2, dn3, f3, f4, 90, 160, 160, 45, 80, P);
  pyrdown_lds_k<<<pgrd(40, 23, P), blk, 0, stream>>>(
      dn3, dn4, nullptr, nullptr, 45, 80, 80, 23, 40, P);
  pyrdown_lds_k<<<pgrd(20, 12, P), blk, 0, stream>>>(
      dn4, dn5, nullptr, nullptr, 23, 40, 40, 12, 20, P);

  // ---- fused reconstruction (coarse -> fine); grid = (Wc/2, Hc) ----
  recon4_k<<<grd(10, 12, P), blk, 0, stream>>>(
      dn5, dn5, 12, 20, dn4, f4, 45, 80, 80, fix, 1.0f / 16.0f, fv4, 23, 40);
  recon4_k<<<grd(20, 23, P), blk, 0, stream>>>(
      fv4, dn4, 23, 40, dn3, f3, 90, 160, 160, fix, 1.0f / 8.0f, fv3, 45, 80);
  recon4_k<<<grd(40, 45, P), blk, 0, stream>>>(
      fv3, dn3, 45, 80, dn2, f2, 180, 320, 320, fix, 0.25f, fv2, 90, 160);
  recon4_k<<<grd(80, 90, P), blk, 0, stream>>>(
      fv2, dn2, 90, 160, dn1, f1, 360, 640, 640, fix, 0.5f, fv1, 180, 320);
  recon4_k<<<grd(160, 180, P), blk, 0, stream>>>(
      fv1, dn1, 180, 320, images, f0, 719, 1279, 1280, fix, 1.0f, out, 360, 640);
}